// Round 11
// baseline (320.289 us; speedup 1.0000x reference)
//
#include <hip/hip_runtime.h>
#include <math.h>

#define NPTS  65536
#define KNN   10
#define PK    25
#define NCOUT 64
#define GRIDB 10          // pooling grid (cell 0.1) — must match reference
#define NSEG  1000
#define GRIDC 20          // kNN search grid (cell 0.05)
#define NCELL 8000
#define CELLK 0.05f
#define R0SQ  0.002025f   // 0.045^2 collect radius: E[in-ball]=25 interior
#define SLAB_CAP 832      // 9 cols x ~9 z-cells: mean ~663
#define QCAP  16          // per-stripe per-query list cap (stripe E[hits]=6.3)
#define LSTR  17          // list stride in u16 (odd*... -> ~2 lanes/bank, free)
#define INVSIG (1.0f / (2.1f * 0.05f))

// ---- workspace layout (bytes) ----
#define OFF_SORTED  0           // float4 sorted[65536]
#define OFF_HIST    1048576     // int hist[8000]
#define OFF_UCNT    1080576     // int unresolved count
#define OFF_CSTART  1080580     // int cstart[8001]
#define OFF_CURSOR  1112584     // int cursor[8000]
#define OFF_ULST    1144584     // int ulst[65536]
#define OFF_KNN     1406736     // u16 knn[65536][16] (10 used), 16B-aligned rows
#define MEMSET_SIZE 32004       // hist + ucnt contiguous

__device__ __forceinline__ int cell_of(float px, float py, float pz) {
    int gx = min((int)(px * (float)GRIDC), GRIDC - 1);
    int gy = min((int)(py * (float)GRIDC), GRIDC - 1);
    int gz = min((int)(pz * (float)GRIDC), GRIDC - 1);
    return (gx * GRIDC + gy) * GRIDC + gz;
}

__global__ __launch_bounds__(256) void hist_kernel(
    const float* __restrict__ pts, int* __restrict__ hist)
{
    int g = blockIdx.x * 256 + threadIdx.x;
    float px = pts[g*3+0], py = pts[g*3+1], pz = pts[g*3+2];
    atomicAdd(&hist[cell_of(px, py, pz)], 1);
}

__global__ __launch_bounds__(256) void scan_kernel(
    const int* __restrict__ hist, int* __restrict__ cstart, int* __restrict__ cursor)
{
    __shared__ int part[256];
    const int t = threadIdx.x;
    const int base = t * 32;
    int s = 0;
    for (int i = 0; i < 32; ++i) {
        int c = base + i;
        s += (c < NCELL) ? hist[c] : 0;
    }
    part[t] = s;
    __syncthreads();
    for (int off = 1; off < 256; off <<= 1) {
        int v = (t >= off) ? part[t - off] : 0;
        __syncthreads();
        part[t] += v;
        __syncthreads();
    }
    int run = (t == 0) ? 0 : part[t - 1];
    for (int i = 0; i < 32; ++i) {
        int c = base + i;
        if (c < NCELL) {
            cstart[c] = run;
            cursor[c] = run;
            run += hist[c];
        }
    }
    if (t == 255) cstart[NCELL] = run;
}

__global__ __launch_bounds__(256) void scatter_kernel(
    const float* __restrict__ pts, int* __restrict__ cursor, float4* __restrict__ sorted)
{
    int g = blockIdx.x * 256 + threadIdx.x;
    float px = pts[g*3+0], py = pts[g*3+1], pz = pts[g*3+2];
    int c = cell_of(px, py, pz);
    int pos = atomicAdd(&cursor[c], 1);
    sorted[pos] = make_float4(px, py, pz, 0.f);
}

__device__ __forceinline__ void insert10(float (&kd)[KNN], int (&ki)[KNN],
                                         float d, int idx)
{
    float cd = d; int ci = idx;
#pragma unroll
    for (int u = 0; u < KNN; ++u) {
        bool lt = cd < kd[u];                  // strict: stable (earlier wins ties)
        float td = kd[u]; int ti = ki[u];
        kd[u] = lt ? cd : kd[u];
        ki[u] = lt ? ci : ki[u];
        cd = lt ? td : cd;
        ci = lt ? ti : ci;
    }
}

__device__ __forceinline__ void ins10_64(unsigned long long (&kd)[KNN],
                                         unsigned long long v) {
#pragma unroll
    for (int u = 0; u < KNN; ++u) {
        bool lt = v < kd[u];
        unsigned long long lo = lt ? v : kd[u];
        unsigned long long hi = lt ? kd[u] : v;
        kd[u] = lo; v = hi;
    }
}

// ---- A: one 4-wave block per z-column segment; lane = query; wave = slab stripe.
// Same total ds_read count as 1-wave version, 4x the latency-hiding waves.
__global__ __launch_bounds__(256) void knn_kernel(
    const float4* __restrict__ sorted,
    const int*    __restrict__ cstart,
    unsigned short* __restrict__ knn,
    int*          __restrict__ ucnt,
    int*          __restrict__ ulst)
{
    __shared__ float4 cand[SLAB_CAP];                 // 13312 B (.w = |s|^2)
    __shared__ unsigned short gidx[SLAB_CAP];         // 1664 B (global idx)
    __shared__ unsigned short lst[256 * LSTR];        // 8704 B
    __shared__ unsigned char  cntS[256];              // 256 B

    const int tid  = threadIdx.x;
    const int wv   = tid >> 6;
    const int lane = tid & 63;
    const int col = blockIdx.x / 3;
    const int seg = blockIdx.x % 3;
    const int cx = col / GRIDC, cy = col % GRIDC;
    const int cz0 = (seg < 2) ? seg * 7 : 14;
    const int len = (seg < 2) ? 7 : 6;
    const int colBase = col * GRIDC;

    const int qb = cstart[colBase + cz0];
    const int qe = cstart[colBase + cz0 + len];
    const int qn = qe - qb;
    if (qn == 0) return;

    const int zA = max(cz0 - 1, 0);
    const int zB = min(cz0 + len, GRIDC - 1);

    int cB4 = 0, cS4 = 0;
    int ncand = 0;
    {
        int cB[9], cS[9], cL[9];
#pragma unroll
        for (int a = 0; a < 3; ++a)
#pragma unroll
            for (int b = 0; b < 3; ++b) {
                int c = a * 3 + b;
                int xx = cx - 1 + a, yy = cy - 1 + b;
                bool v = ((unsigned)xx < GRIDC) && ((unsigned)yy < GRIDC);
                int cc = v ? (xx * GRIDC + yy) * GRIDC : 0;
                int s0 = v ? cstart[cc + zA] : 0;
                int e0 = v ? cstart[cc + zB + 1] : 0;
                cS[c] = s0; cB[c] = ncand; cL[c] = e0 - s0;
                ncand += e0 - s0;
            }
        cB4 = cB[4]; cS4 = cS[4];
#pragma unroll
        for (int c = 0; c < 9; ++c) {
            int lim = min(cL[c], max(0, SLAB_CAP - cB[c]));
            for (int i = tid; i < lim; i += 256) {
                float4 p = sorted[cS[c] + i];
                gidx[cB[c] + i] = (unsigned short)(cS[c] + i);
                p.w = p.x*p.x + p.y*p.y + p.z*p.z;    // |s|^2
                cand[cB[c] + i] = p;
            }
        }
    }
    const bool slabOvf = (ncand > SLAB_CAP);
    const int nscan = min(ncand, SLAB_CAP);
    __syncthreads();

    const int sw = (nscan * wv) >> 2;         // this wave's stripe
    const int ew = (nscan * (wv + 1)) >> 2;
    const int lb = tid * LSTR;

    for (int qbase = 0; qbase < qn; qbase += 64) {
        const bool active = (qbase + lane) < qn;
        const int qidx = qb + qbase + (active ? lane : 0);

        if (slabOvf) {            // degenerate (P~1e-11): all to phase B
            if (active && wv == 0) ulst[atomicAdd(ucnt, 1)] = qidx;
            continue;             // block-uniform: no divergent sync
        }

        const float4 Q = cand[cB4 + (qidx - cS4)];
        const float qq = Q.w;
        const float m2x = -2.f*Q.x, m2y = -2.f*Q.y, m2z = -2.f*Q.z;

        // ---- collect (branchless): wave scans its stripe for all 64 queries
        int cnt = 0;
#pragma unroll 4
        for (int j = sw; j < ew; ++j) {
            float4 s = cand[j];
            float t = fmaf(m2x, s.x, s.w);
            t = fmaf(m2y, s.y, t);
            t = fmaf(m2z, s.z, t);
            float d = t + qq;
            lst[lb + min(cnt, QCAP - 1)] = (unsigned short)j;  // always write
            cnt += (d < R0SQ) ? 1 : 0;
        }
        cntS[tid] = (unsigned char)min(cnt, 255);
        __syncthreads();

        // ---- select on wave 0: merge 4 stripe lists (ascending slab idx)
        if (wv == 0) {
            int c0 = cntS[lane], c1 = cntS[64 + lane],
                c2 = cntS[128 + lane], c3 = cntS[192 + lane];
            int total = c0 + c1 + c2 + c3;
            bool ok = active && total >= KNN &&
                      c0 <= QCAP && c1 <= QCAP && c2 <= QCAP && c3 <= QCAP;
            if (active && !ok) ulst[atomicAdd(ucnt, 1)] = qidx;

            if (ok) {
                float kd[KNN]; int ki[KNN];
#pragma unroll
                for (int u = 0; u < KNN; ++u) { kd[u] = 3.4e38f; ki[u] = 0; }
#pragma unroll
                for (int w = 0; w < 4; ++w) {
                    int cw = (w == 0) ? c0 : (w == 1) ? c1 : (w == 2) ? c2 : c3;
                    int wb = (w * 64 + lane) * LSTR;
                    for (int i = 0; i < cw; ++i) {
                        int j = lst[wb + i];
                        float4 s = cand[j];
                        float t = fmaf(m2x, s.x, s.w);
                        t = fmaf(m2y, s.y, t);
                        t = fmaf(m2z, s.z, t);
                        float d = t + qq;
                        if (d < kd[KNN-1]) insert10(kd, ki, d, j);
                    }
                }
#pragma unroll
                for (int u = 0; u < KNN; ++u)
                    knn[qidx * 16 + u] = gidx[ki[u]];
            }
        }
        __syncthreads();          // lst reused next pass
    }
}

// ---- B: one wave per unresolved query; exact ring window; writes knn only
__global__ __launch_bounds__(64) void phaseB(
    const float4* __restrict__ sorted,
    const int*    __restrict__ cstart,
    unsigned short* __restrict__ knn,
    const int*    __restrict__ ucnt,
    const int*    __restrict__ ulst)
{
    const int lane = threadIdx.x;
    const int n = *ucnt;

    for (int w = blockIdx.x; w < n; w += gridDim.x) {
        const int qidx = ulst[w];
        const float4 Q = sorted[qidx];
        const int cqx = min((int)(Q.x * (float)GRIDC), GRIDC - 1);
        const int cqy = min((int)(Q.y * (float)GRIDC), GRIDC - 1);
        const int cqz = min((int)(Q.z * (float)GRIDC), GRIDC - 1);

        int r = 2;
        while (true) {
            unsigned long long kd[KNN];
#pragma unroll
            for (int u = 0; u < KNN; ++u) kd[u] = ~0ull;
            const int x0 = max(cqx-r,0), x1 = min(cqx+r,GRIDC-1);
            const int y0 = max(cqy-r,0), y1 = min(cqy+r,GRIDC-1);
            const int z0 = max(cqz-r,0), z1 = min(cqz+r,GRIDC-1);
            for (int xx = x0; xx <= x1; ++xx)
                for (int yy = y0; yy <= y1; ++yy) {
                    const int cc = (xx * GRIDC + yy) * GRIDC;
                    const int b0 = cstart[cc + z0], e0 = cstart[cc + z1 + 1];
                    for (int i = b0 + lane; i < e0; i += 64) {   // coalesced
                        float4 s = sorted[i];
                        float dx = Q.x - s.x, dy = Q.y - s.y, dz = Q.z - s.z;
                        float d = dx * dx;
                        d = fmaf(dy, dy, d);
                        d = fmaf(dz, dz, d);
                        unsigned long long pk =
                            ((unsigned long long)__float_as_uint(d) << 32) | (unsigned)i;
                        if (pk < kd[KNN-1]) ins10_64(kd, pk);
                    }
                }
            // wave-wide top-10: 10 rounds {wave-min of kd[0]; winner shifts down}
            float d10 = 0.f;
#pragma unroll
            for (int t = 0; t < KNN; ++t) {
                unsigned long long m = kd[0];
#pragma unroll
                for (int off = 1; off < 64; off <<= 1) {
                    unsigned long long o = __shfl_xor(m, off);
                    m = (o < m) ? o : m;
                }
                if (lane == 0) knn[qidx * 16 + t] = (unsigned short)(unsigned)m;
                d10 = __uint_as_float((unsigned)(m >> 32));
                bool win = (kd[0] == m);          // unique (idx in low bits)
#pragma unroll
                for (int u = 0; u < KNN-1; ++u) kd[u] = win ? kd[u+1] : kd[u];
                kd[KNN-1] = win ? ~0ull : kd[KNN-1];
            }
            float rr = r * CELLK;
            if (d10 <= rr * rr || r >= GRIDC) break;   // NaN-safe
            ++r;
        }
    }
}

// ---- C: one block per pool voxel; influence + reduce + W-matmul + store.
__global__ __launch_bounds__(64) void gather_pool(
    const float4* __restrict__ sorted,
    const int*    __restrict__ cstart,
    const unsigned short* __restrict__ knn,
    const float*  __restrict__ kern,
    const float*  __restrict__ W,
    float*        __restrict__ out)
{
    __shared__ float kx[PK], ky[PK], kz[PK];
    const int lane = threadIdx.x;
    const int s = blockIdx.x;
    const int Z = s % GRIDB, Y = (s / GRIDB) % GRIDB, X = s / (GRIDB * GRIDB);

    if (lane < PK) { kx[lane]=kern[lane*3]; ky[lane]=kern[lane*3+1]; kz[lane]=kern[lane*3+2]; }
    __syncthreads();

    int rb[4], rl[4];
#pragma unroll
    for (int a = 0; a < 2; ++a)
#pragma unroll
        for (int b = 0; b < 2; ++b) {
            int cc = ((2*X + a) * GRIDC + (2*Y + b)) * GRIDC + 2*Z;
            int b0 = cstart[cc], e0 = cstart[cc + 2];
            rb[a*2+b] = b0; rl[a*2+b] = e0 - b0;
        }
    const int c0 = rl[0], c1 = c0 + rl[1], c2 = c1 + rl[2];
    const int qn = c2 + rl[3];

    float acc[PK];
#pragma unroll
    for (int p = 0; p < PK; ++p) acc[p] = 0.f;
    float cntL = 0.f, sxL = 0.f, syL = 0.f, szL = 0.f;

    for (int base = 0; base < qn; base += 64) {
        int i = base + lane;
        if (i < qn) {
            int qidx;
            if (i < c0)      qidx = rb[0] + i;
            else if (i < c1) qidx = rb[1] + (i - c0);
            else if (i < c2) qidx = rb[2] + (i - c1);
            else             qidx = rb[3] + (i - c2);

            float4 Q = sorted[qidx];
            const unsigned short* kr = knn + qidx * 16;
            int4 v  = *reinterpret_cast<const int4*>(kr);
            int  v2 = *reinterpret_cast<const int*>(kr + 8);

#pragma unroll
            for (int u = 0; u < KNN; ++u) {
                int w32 = (u < 2) ? v.x : (u < 4) ? v.y : (u < 6) ? v.z
                        : (u < 8) ? v.w : v2;
                int idx = (u & 1) ? ((w32 >> 16) & 0xFFFF) : (w32 & 0xFFFF);
                float4 nb = sorted[idx];
                float rx = nb.x - Q.x, ry = nb.y - Q.y, rz = nb.z - Q.z;
#pragma unroll
                for (int p = 0; p < PK; ++p) {
                    float dx = rx - kx[p], dy = ry - ky[p], dz = rz - kz[p];
                    float d2 = dx * dx;
                    d2 = fmaf(dy, dy, d2);
                    d2 = fmaf(dz, dz, d2);
                    acc[p] += fmaxf(0.f, fmaf(-INVSIG, sqrtf(d2), 1.f));
                }
            }
            cntL += 1.f; sxL += Q.x; syL += Q.y; szL += Q.z;
        }
    }

    // butterfly reduce 29 sums across the wave (all lanes get totals)
#pragma unroll
    for (int off = 1; off < 64; off <<= 1) {
        cntL += __shfl_xor(cntL, off);
        sxL  += __shfl_xor(sxL, off);
        syL  += __shfl_xor(syL, off);
        szL  += __shfl_xor(szL, off);
#pragma unroll
        for (int p = 0; p < PK; ++p) acc[p] += __shfl_xor(acc[p], off);
    }

    const float inv = 1.0f / fmaxf(cntL, 1.0f);
    float dotv = 0.f;
#pragma unroll
    for (int p = 0; p < PK; ++p) dotv = fmaf(acc[p], W[p * NCOUT + lane], dotv);
    out[NSEG*3 + s*NCOUT + lane] = dotv * inv;
    if (lane == 0) {
        out[s*3+0] = sxL * inv;
        out[s*3+1] = syL * inv;
        out[s*3+2] = szL * inv;
    }
}

extern "C" void kernel_launch(void* const* d_in, const int* in_sizes, int n_in,
                              void* d_out, int out_size, void* d_ws, size_t ws_size,
                              hipStream_t stream)
{
    const float* pts  = (const float*)d_in[0];
    const float* kern = (const float*)d_in[1];
    const float* W    = (const float*)d_in[2];
    float* out = (float*)d_out;
    char*  ws  = (char*)d_ws;

    float4* sorted = (float4*)(ws + OFF_SORTED);
    int*    hist   = (int*)   (ws + OFF_HIST);
    int*    ucnt   = (int*)   (ws + OFF_UCNT);
    int*    cstart = (int*)   (ws + OFF_CSTART);
    int*    cursor = (int*)   (ws + OFF_CURSOR);
    int*    ulst   = (int*)   (ws + OFF_ULST);
    unsigned short* knn = (unsigned short*)(ws + OFF_KNN);

    hipMemsetAsync(hist, 0, MEMSET_SIZE, stream);   // hist + ucnt

    hist_kernel   <<<NPTS/256, 256, 0, stream>>>(pts, hist);
    scan_kernel   <<<1,        256, 0, stream>>>(hist, cstart, cursor);
    scatter_kernel<<<NPTS/256, 256, 0, stream>>>(pts, cursor, sorted);
    knn_kernel    <<<400*3,    256, 0, stream>>>(sorted, cstart, knn, ucnt, ulst);
    phaseB        <<<2048,      64, 0, stream>>>(sorted, cstart, knn, ucnt, ulst);
    gather_pool   <<<NSEG,      64, 0, stream>>>(sorted, cstart, knn, kern, W, out);
}

// Round 12
// 206.048 us; speedup vs baseline: 1.5544x; 1.5544x over previous
//
#include <hip/hip_runtime.h>
#include <math.h>

#define NPTS  65536
#define KNN   10
#define PK    25
#define NCOUT 64
#define GRIDB 10          // pooling grid (cell 0.1) — must match reference
#define NSEG  1000
#define GRIDC 20          // kNN search grid (cell 0.05)
#define NCELL 8000
#define CELLK 0.05f
#define NSEGZ 5           // z-segments per column (4 cells each)
#define SEGL  4
#define R0SQ  0.0025f     // 0.05^2 collect radius: E[in-ball]=34.3; exact bound
#define SLAB_CAP 576      // 9 cols x 6 z-cells: mean ~442 (+6.4 sigma)
#define LIST_CAP 64       // E=34.3, P(>64) ~ 1e-6
#define LIST_STRIDE 65
#define INVSIG (1.0f / (2.1f * 0.05f))

// ---- workspace layout (bytes) ----
#define OFF_SORTED  0           // float4 sorted[65536]
#define OFF_HIST    1048576     // int hist[8000]
#define OFF_UCNT    1080576     // int unresolved count
#define OFF_CSTART  1080580     // int cstart[8001]
#define OFF_CURSOR  1112584     // int cursor[8000]
#define OFF_ULST    1144584     // int ulst[65536]
#define OFF_KNN     1406736     // u16 knn[65536][16] (10 used)
#define MEMSET_SIZE 32004       // hist + ucnt contiguous

__device__ __forceinline__ int cell_of(float px, float py, float pz) {
    int gx = min((int)(px * (float)GRIDC), GRIDC - 1);
    int gy = min((int)(py * (float)GRIDC), GRIDC - 1);
    int gz = min((int)(pz * (float)GRIDC), GRIDC - 1);
    return (gx * GRIDC + gy) * GRIDC + gz;
}

__global__ __launch_bounds__(256) void hist_kernel(
    const float* __restrict__ pts, int* __restrict__ hist)
{
    int g = blockIdx.x * 256 + threadIdx.x;
    float px = pts[g*3+0], py = pts[g*3+1], pz = pts[g*3+2];
    atomicAdd(&hist[cell_of(px, py, pz)], 1);
}

__global__ __launch_bounds__(256) void scan_kernel(
    const int* __restrict__ hist, int* __restrict__ cstart, int* __restrict__ cursor)
{
    __shared__ int part[256];
    const int t = threadIdx.x;
    const int base = t * 32;
    int s = 0;
    for (int i = 0; i < 32; ++i) {
        int c = base + i;
        s += (c < NCELL) ? hist[c] : 0;
    }
    part[t] = s;
    __syncthreads();
    for (int off = 1; off < 256; off <<= 1) {
        int v = (t >= off) ? part[t - off] : 0;
        __syncthreads();
        part[t] += v;
        __syncthreads();
    }
    int run = (t == 0) ? 0 : part[t - 1];
    for (int i = 0; i < 32; ++i) {
        int c = base + i;
        if (c < NCELL) {
            cstart[c] = run;
            cursor[c] = run;
            run += hist[c];
        }
    }
    if (t == 255) cstart[NCELL] = run;
}

__global__ __launch_bounds__(256) void scatter_kernel(
    const float* __restrict__ pts, int* __restrict__ cursor, float4* __restrict__ sorted)
{
    int g = blockIdx.x * 256 + threadIdx.x;
    float px = pts[g*3+0], py = pts[g*3+1], pz = pts[g*3+2];
    int c = cell_of(px, py, pz);
    int pos = atomicAdd(&cursor[c], 1);
    sorted[pos] = make_float4(px, py, pz, 0.f);
}

__device__ __forceinline__ void insert10(float (&kd)[KNN], int (&ki)[KNN],
                                         float d, int idx)
{
    float cd = d; int ci = idx;
#pragma unroll
    for (int u = 0; u < KNN; ++u) {
        bool lt = cd < kd[u];                  // strict: stable (earlier wins ties)
        float td = kd[u]; int ti = ki[u];
        kd[u] = lt ? cd : kd[u];
        ki[u] = lt ? ci : ki[u];
        cd = lt ? td : cd;
        ci = lt ? ti : ci;
    }
}

__device__ __forceinline__ void ins10_64(unsigned long long (&kd)[KNN],
                                         unsigned long long v) {
#pragma unroll
    for (int u = 0; u < KNN; ++u) {
        bool lt = v < kd[u];
        unsigned long long lo = lt ? v : kd[u];
        unsigned long long hi = lt ? kd[u] : v;
        kd[u] = lo; v = hi;
    }
}

// ---- A: one wave per z-column segment (5 segs of 4 cells); lane = query.
// R10-proven branchless collect; r0 = 0.05 resolves nearly all faces too.
__global__ __launch_bounds__(64) void knn_kernel(
    const float4* __restrict__ sorted,
    const int*    __restrict__ cstart,
    unsigned short* __restrict__ knn,
    int*          __restrict__ ucnt,
    int*          __restrict__ ulst)
{
    __shared__ float4 cand[SLAB_CAP];                 // 9216 B (.w = |s|^2)
    __shared__ unsigned short gidx[SLAB_CAP];         // 1152 B (global idx)
    __shared__ unsigned short lst[64 * LIST_STRIDE];  // 8320 B

    const int tid = threadIdx.x;
    const int col = blockIdx.x / NSEGZ;
    const int seg = blockIdx.x % NSEGZ;
    const int cx = col / GRIDC, cy = col % GRIDC;
    const int cz0 = seg * SEGL;
    const int colBase = col * GRIDC;

    const int qb = cstart[colBase + cz0];
    const int qe = cstart[colBase + cz0 + SEGL];
    const int qn = qe - qb;
    if (qn == 0) return;

    const int zA = max(cz0 - 1, 0);
    const int zB = min(cz0 + SEGL, GRIDC - 1);

    int cB4 = 0, cS4 = 0;
    int ncand = 0;
    {
        int cB[9], cS[9], cL[9];
#pragma unroll
        for (int a = 0; a < 3; ++a)
#pragma unroll
            for (int b = 0; b < 3; ++b) {
                int c = a * 3 + b;
                int xx = cx - 1 + a, yy = cy - 1 + b;
                bool v = ((unsigned)xx < GRIDC) && ((unsigned)yy < GRIDC);
                int cc = v ? (xx * GRIDC + yy) * GRIDC : 0;
                int s0 = v ? cstart[cc + zA] : 0;
                int e0 = v ? cstart[cc + zB + 1] : 0;
                cS[c] = s0; cB[c] = ncand; cL[c] = e0 - s0;
                ncand += e0 - s0;
            }
        cB4 = cB[4]; cS4 = cS[4];
#pragma unroll
        for (int c = 0; c < 9; ++c) {
            int lim = min(cL[c], max(0, SLAB_CAP - cB[c]));
            for (int i = tid; i < lim; i += 64) {
                float4 p = sorted[cS[c] + i];
                gidx[cB[c] + i] = (unsigned short)(cS[c] + i);
                p.w = p.x*p.x + p.y*p.y + p.z*p.z;    // |s|^2
                cand[cB[c] + i] = p;
            }
        }
    }
    const bool slabOvf = (ncand > SLAB_CAP);
    const int nscan = min(ncand, SLAB_CAP);
    __syncthreads();

    const int lb = tid * LIST_STRIDE;

    for (int qbase = 0; qbase < qn; qbase += 64) {
        const bool active = (qbase + tid) < qn;
        const int qidx = qb + qbase + (active ? tid : 0);

        if (slabOvf) {            // degenerate: all to phase B
            if (active) ulst[atomicAdd(ucnt, 1)] = qidx;
            continue;
        }

        const float4 Q = cand[cB4 + (qidx - cS4)];
        const float qq = Q.w;
        const float m2x = -2.f*Q.x, m2y = -2.f*Q.y, m2z = -2.f*Q.z;

        // ---- collect: branchless always-write; slots [0,cnt) = hits
        int cnt = 0;
#pragma unroll 4
        for (int j = 0; j < nscan; ++j) {
            float4 s = cand[j];
            float t = fmaf(m2x, s.x, s.w);
            t = fmaf(m2y, s.y, t);
            t = fmaf(m2z, s.z, t);
            float d = t + qq;
            lst[lb + min(cnt, LIST_CAP)] = (unsigned short)j;  // always write
            cnt += (d < R0SQ) ? 1 : 0;
        }

        const bool resolved = active && (cnt >= KNN) && (cnt <= LIST_CAP);
        if (active && !resolved) ulst[atomicAdd(ucnt, 1)] = qidx;

        if (resolved) {
            float kd[KNN]; int ki[KNN];
#pragma unroll
            for (int u = 0; u < KNN; ++u) { kd[u] = 3.4e38f; ki[u] = 0; }
            for (int i = 0; i < cnt; ++i) {
                int j = lst[lb + i];
                float4 s = cand[j];
                float t = fmaf(m2x, s.x, s.w);
                t = fmaf(m2y, s.y, t);
                t = fmaf(m2z, s.z, t);
                float d = t + qq;
                if (d < kd[KNN-1]) insert10(kd, ki, d, j);  // asc j = asc global id
            }
#pragma unroll
            for (int u = 0; u < KNN; ++u)
                knn[qidx * 16 + u] = gidx[ki[u]];
        }
    }
}

// ---- B: one wave per unresolved query; r=3 start (single-pass even for corners)
__global__ __launch_bounds__(64) void phaseB(
    const float4* __restrict__ sorted,
    const int*    __restrict__ cstart,
    unsigned short* __restrict__ knn,
    const int*    __restrict__ ucnt,
    const int*    __restrict__ ulst)
{
    const int lane = threadIdx.x;
    const int n = *ucnt;

    for (int w = blockIdx.x; w < n; w += gridDim.x) {
        const int qidx = ulst[w];
        const float4 Q = sorted[qidx];
        const int cqx = min((int)(Q.x * (float)GRIDC), GRIDC - 1);
        const int cqy = min((int)(Q.y * (float)GRIDC), GRIDC - 1);
        const int cqz = min((int)(Q.z * (float)GRIDC), GRIDC - 1);

        int r = 3;   // window covers ball(0.15); worst-case corner d10^2 ~ 0.018 < 0.0225
        while (true) {
            unsigned long long kd[KNN];
#pragma unroll
            for (int u = 0; u < KNN; ++u) kd[u] = ~0ull;
            const int x0 = max(cqx-r,0), x1 = min(cqx+r,GRIDC-1);
            const int y0 = max(cqy-r,0), y1 = min(cqy+r,GRIDC-1);
            const int z0 = max(cqz-r,0), z1 = min(cqz+r,GRIDC-1);
            for (int xx = x0; xx <= x1; ++xx)
                for (int yy = y0; yy <= y1; ++yy) {
                    const int cc = (xx * GRIDC + yy) * GRIDC;
                    const int b0 = cstart[cc + z0], e0 = cstart[cc + z1 + 1];
                    for (int i = b0 + lane; i < e0; i += 64) {   // coalesced
                        float4 s = sorted[i];
                        float dx = Q.x - s.x, dy = Q.y - s.y, dz = Q.z - s.z;
                        float d = dx * dx;
                        d = fmaf(dy, dy, d);
                        d = fmaf(dz, dz, d);
                        unsigned long long pk =
                            ((unsigned long long)__float_as_uint(d) << 32) | (unsigned)i;
                        if (pk < kd[KNN-1]) ins10_64(kd, pk);
                    }
                }
            // wave-wide top-10: 10 rounds {wave-min of kd[0]; winner shifts down}
            float d10 = 0.f;
#pragma unroll
            for (int t = 0; t < KNN; ++t) {
                unsigned long long m = kd[0];
#pragma unroll
                for (int off = 1; off < 64; off <<= 1) {
                    unsigned long long o = __shfl_xor(m, off);
                    m = (o < m) ? o : m;
                }
                if (lane == 0) knn[qidx * 16 + t] = (unsigned short)(unsigned)m;
                d10 = __uint_as_float((unsigned)(m >> 32));
                bool win = (kd[0] == m);          // unique (idx in low bits)
#pragma unroll
                for (int u = 0; u < KNN-1; ++u) kd[u] = win ? kd[u+1] : kd[u];
                kd[KNN-1] = win ? ~0ull : kd[KNN-1];
            }
            float rr = r * CELLK;
            if (d10 <= rr * rr || r >= GRIDC) break;   // NaN-safe
            r += 2;
        }
    }
}

// ---- C: one block per pool voxel; influence + reduce + W-matmul + store.
__global__ __launch_bounds__(64) void gather_pool(
    const float4* __restrict__ sorted,
    const int*    __restrict__ cstart,
    const unsigned short* __restrict__ knn,
    const float*  __restrict__ kern,
    const float*  __restrict__ W,
    float*        __restrict__ out)
{
    __shared__ float kx[PK], ky[PK], kz[PK];
    const int lane = threadIdx.x;
    const int s = blockIdx.x;
    const int Z = s % GRIDB, Y = (s / GRIDB) % GRIDB, X = s / (GRIDB * GRIDB);

    if (lane < PK) { kx[lane]=kern[lane*3]; ky[lane]=kern[lane*3+1]; kz[lane]=kern[lane*3+2]; }
    __syncthreads();

    int rb[4], rl[4];
#pragma unroll
    for (int a = 0; a < 2; ++a)
#pragma unroll
        for (int b = 0; b < 2; ++b) {
            int cc = ((2*X + a) * GRIDC + (2*Y + b)) * GRIDC + 2*Z;
            int b0 = cstart[cc], e0 = cstart[cc + 2];
            rb[a*2+b] = b0; rl[a*2+b] = e0 - b0;
        }
    const int c0 = rl[0], c1 = c0 + rl[1], c2 = c1 + rl[2];
    const int qn = c2 + rl[3];

    float acc[PK];
#pragma unroll
    for (int p = 0; p < PK; ++p) acc[p] = 0.f;
    float cntL = 0.f, sxL = 0.f, syL = 0.f, szL = 0.f;

    for (int base = 0; base < qn; base += 64) {
        int i = base + lane;
        if (i < qn) {
            int qidx;
            if (i < c0)      qidx = rb[0] + i;
            else if (i < c1) qidx = rb[1] + (i - c0);
            else if (i < c2) qidx = rb[2] + (i - c1);
            else             qidx = rb[3] + (i - c2);

            float4 Q = sorted[qidx];
            const unsigned short* kr = knn + qidx * 16;
            int4 v  = *reinterpret_cast<const int4*>(kr);
            int  v2 = *reinterpret_cast<const int*>(kr + 8);

#pragma unroll
            for (int u = 0; u < KNN; ++u) {
                int w32 = (u < 2) ? v.x : (u < 4) ? v.y : (u < 6) ? v.z
                        : (u < 8) ? v.w : v2;
                int idx = (u & 1) ? ((w32 >> 16) & 0xFFFF) : (w32 & 0xFFFF);
                float4 nb = sorted[idx];
                float rx = nb.x - Q.x, ry = nb.y - Q.y, rz = nb.z - Q.z;
#pragma unroll
                for (int p = 0; p < PK; ++p) {
                    float dx = rx - kx[p], dy = ry - ky[p], dz = rz - kz[p];
                    float d2 = dx * dx;
                    d2 = fmaf(dy, dy, d2);
                    d2 = fmaf(dz, dz, d2);
                    acc[p] += fmaxf(0.f, fmaf(-INVSIG, sqrtf(d2), 1.f));
                }
            }
            cntL += 1.f; sxL += Q.x; syL += Q.y; szL += Q.z;
        }
    }

    // butterfly reduce 29 sums across the wave (all lanes get totals)
#pragma unroll
    for (int off = 1; off < 64; off <<= 1) {
        cntL += __shfl_xor(cntL, off);
        sxL  += __shfl_xor(sxL, off);
        syL  += __shfl_xor(syL, off);
        szL  += __shfl_xor(szL, off);
#pragma unroll
        for (int p = 0; p < PK; ++p) acc[p] += __shfl_xor(acc[p], off);
    }

    const float inv = 1.0f / fmaxf(cntL, 1.0f);
    float dotv = 0.f;
#pragma unroll
    for (int p = 0; p < PK; ++p) dotv = fmaf(acc[p], W[p * NCOUT + lane], dotv);
    out[NSEG*3 + s*NCOUT + lane] = dotv * inv;
    if (lane == 0) {
        out[s*3+0] = sxL * inv;
        out[s*3+1] = syL * inv;
        out[s*3+2] = szL * inv;
    }
}

extern "C" void kernel_launch(void* const* d_in, const int* in_sizes, int n_in,
                              void* d_out, int out_size, void* d_ws, size_t ws_size,
                              hipStream_t stream)
{
    const float* pts  = (const float*)d_in[0];
    const float* kern = (const float*)d_in[1];
    const float* W    = (const float*)d_in[2];
    float* out = (float*)d_out;
    char*  ws  = (char*)d_ws;

    float4* sorted = (float4*)(ws + OFF_SORTED);
    int*    hist   = (int*)   (ws + OFF_HIST);
    int*    ucnt   = (int*)   (ws + OFF_UCNT);
    int*    cstart = (int*)   (ws + OFF_CSTART);
    int*    cursor = (int*)   (ws + OFF_CURSOR);
    int*    ulst   = (int*)   (ws + OFF_ULST);
    unsigned short* knn = (unsigned short*)(ws + OFF_KNN);

    hipMemsetAsync(hist, 0, MEMSET_SIZE, stream);   // hist + ucnt

    hist_kernel   <<<NPTS/256, 256, 0, stream>>>(pts, hist);
    scan_kernel   <<<1,        256, 0, stream>>>(hist, cstart, cursor);
    scatter_kernel<<<NPTS/256, 256, 0, stream>>>(pts, cursor, sorted);
    knn_kernel    <<<400*NSEGZ, 64, 0, stream>>>(sorted, cstart, knn, ucnt, ulst);
    phaseB        <<<4096,      64, 0, stream>>>(sorted, cstart, knn, ucnt, ulst);
    gather_pool   <<<NSEG,      64, 0, stream>>>(sorted, cstart, knn, kern, W, out);
}